// Round 2
// baseline (580.013 us; speedup 1.0000x reference)
//
#include <hip/hip_runtime.h>
#include <math.h>

#define SUBS 20
#define TAPS 201
#define ENO 2000
#define INO 500
#define TDATA 20000

typedef __bf16 bf16x8 __attribute__((ext_vector_type(8)));
typedef float f32x4 __attribute__((ext_vector_type(4)));

#define WGE_STRIDE 2048
#define WGI_STRIDE 512

// workspace byte offsets
#define WGE_OFF  0ull                    // ushort[64*2048] bf16 weights (E)
#define WGI_OFF  262144ull               // ushort[64*512]  bf16 weights (I)
#define KERN_OFF 327680ull               // float[40*201]   synapse kernels
#define INE_OFF  360448ull               // float[60*20000] filtered-input E
#define INI_OFF  (INE_OFF + 4800000ull)  // float[60*20000] filtered-input I
#define SYN_OFF  (INI_OFF + 4800000ull)  // float[60*20000] syn_in per (var,s)

#define ZERO_BLOCKS 117

__device__ __forceinline__ unsigned short f2bf(float f) {
  union { float f; unsigned int u; } c; c.f = f;
  unsigned int u = c.u;
  return (unsigned short)((u + 0x7FFFu + ((u >> 16) & 1u)) >> 16);  // RTNE
}

// ---------------------------------------------------------------------------
// K1: per-column prep (theta, hard/soft/softb) + kern filters + weight pads
//     + zero the in_e/in_i accumulator span (split-K GEMM atomically adds)
// ---------------------------------------------------------------------------
__global__ __launch_bounds__(256) void prep_kernel(
    const float* __restrict__ u, const float* __restrict__ v,
    const float* __restrict__ C_log, const float* __restrict__ W_syn,
    const float* __restrict__ Tau_syn, const float* __restrict__ Delta_syn,
    float* __restrict__ out,
    unsigned short* __restrict__ wge, unsigned short* __restrict__ wgi,
    float* __restrict__ kern, float* __restrict__ in_e)
{
  if (blockIdx.x < 10) {
    const int n = blockIdx.x * 256 + threadIdx.x;
    if (n >= 2500) return;
    float x[SUBS], theta[SUBS], rebar[SUBS];
    float mx = -1e30f;
#pragma unroll
    for (int s = 0; s < SUBS; ++s) { x[s] = C_log[s*2500 + n]; mx = fmaxf(mx, x[s]); }
    float sum = 0.f;
#pragma unroll
    for (int s = 0; s < SUBS; ++s) { theta[s] = expf(x[s] - mx); sum += theta[s]; }
    const float inv = 1.f / sum;
    int idx = 0; float best = -1e30f;
#pragma unroll
    for (int s = 0; s < SUBS; ++s) {
      theta[s] *= inv;
      out[60000 + s*2500 + n] = theta[s];
      const float uu = u[s*2500 + n];
      const float r = logf(theta[s]) - logf(-logf(uu));
      rebar[s] = r;
      if (r > best) { best = r; idx = s; }   // first-wins strict >
    }
    const float lvk = logf(v[idx*2500 + n]);
#pragma unroll
    for (int s = 0; s < SUBS; ++s) {
      const float hz = (s == idx) ? 1.f : 0.f;
      const float sz = 1.f / (1.f + expf(-2.f * rebar[s])) + 1e-9f;
      const float vv = v[s*2500 + n];
      const float zb = (s == idx) ? (-logf(-logf(vv)))
                                  : (-logf(-logf(vv) / theta[s] - lvk));
      const float szb = 1.f / (1.f + expf(-2.f * zb)) + 1e-9f;
      out[110000 + s*2500 + n] = hz;
      out[160000 + s*2500 + n] = sz;
      out[210000 + s*2500 + n] = szb;
      if (n < ENO) {
        wge[(s     )*WGE_STRIDE + n] = f2bf(hz);
        wge[(20 + s)*WGE_STRIDE + n] = f2bf(sz);
        wge[(40 + s)*WGE_STRIDE + n] = f2bf(szb);
      } else {
        const int k = n - ENO;
        wgi[(s     )*WGI_STRIDE + k] = f2bf(hz);
        wgi[(20 + s)*WGI_STRIDE + k] = f2bf(sz);
        wgi[(40 + s)*WGI_STRIDE + k] = f2bf(szb);
      }
    }
  } else if (blockIdx.x == 10) {
    const int tid = threadIdx.x;
    for (int i = tid; i < 40*TAPS; i += 256) {
      const int ch = i / TAPS, m = i - ch*TAPS;
      const float dl  = expf(Delta_syn[ch]);
      const float tau = expf(Tau_syn[ch]);
      const float t  = fmaxf((float)m - dl, 0.f);
      const float tt = t / tau;
      kern[i] = tt * expf(-tt) * W_syn[ch];
    }
    // zero the padded weight regions (ws is poisoned 0xAA every launch)
    for (int i = tid; i < 4*2048; i += 256) wge[(60 + (i >> 11))*WGE_STRIDE + (i & 2047)] = 0;
    for (int i = tid; i < 60*48;  i += 256) wge[(i / 48)*WGE_STRIDE + 2000 + (i % 48)] = 0;
    for (int i = tid; i < 4*512;  i += 256) wgi[(60 + (i >> 9))*WGI_STRIDE + (i & 511)] = 0;
    for (int i = tid; i < 60*12;  i += 256) wgi[(i / 12)*WGI_STRIDE + 500 + (i % 12)] = 0;
  } else {
    // zero in_e AND in_i (contiguous 9.6 MB span starting at in_e)
    const int zb = blockIdx.x - 11;
    const int total4 = (2 * 60 * TDATA) / 4;          // 600000 float4
    const float4 z = make_float4(0.f, 0.f, 0.f, 0.f);
    for (int i = zb*256 + threadIdx.x; i < total4; i += ZERO_BLOCKS*256)
      ((float4*)in_e)[i] = z;
  }
}

// ---------------------------------------------------------------------------
// K2: bf16 MFMA GEMM, split-K.  IN[c][t] = sum_k S[t][k] * Wg[c][k]
//     grid.x = t-tile (64 t), grid.y = chunk: 0..3 = E (512 k each), 4 = I
//     E chunks atomicAdd fp32 partials into pre-zeroed in_e; I stores.
// ---------------------------------------------------------------------------
__global__ __launch_bounds__(256) void gemm_kernel(
    const float* __restrict__ S_e, const float* __restrict__ S_i,
    const unsigned short* __restrict__ wge, const unsigned short* __restrict__ wgi,
    float* __restrict__ in_e, float* __restrict__ in_i)
{
  __shared__ union {
    struct { unsigned short A[64*40]; unsigned short B[64*40]; } s;  // [row][k]
    float C[64*67];                                                  // [c][t] pad 67
  } lds;
  const int tid  = threadIdx.x;
  const int t0   = blockIdx.x * 64;
  const int chunk = blockIdx.y;          // 0..3 = E, 4 = I
  const bool isE = (chunk < 4);
  const int wave = tid >> 6;
  const int lane = tid & 63;
  const int m16  = lane & 15;
  const int quad = lane >> 4;
  const int slotA = tid & 7;   // float4 slot along k
  const int rowA  = tid >> 3;  // 32 rows/pass
  const int cB    = tid >> 2;
  const int slotB = tid & 3;

  const float* S = isE ? S_e : S_i;
  const unsigned short* Wg = isE ? wgi : wgi;  // fixed below
  Wg = isE ? wge : wgi;
  float* outp = isE ? in_e : in_i;
  const int K       = isE ? ENO : INO;
  const int Wstride = isE ? WGE_STRIDE : WGI_STRIDE;
  const int k_base  = isE ? chunk * 512 : 0;
  const int steps   = (chunk == 3) ? 15 : 16;   // chunk3 covers k 1536..2015 (pad>2000)

  f32x4 acc0 = {0.f,0.f,0.f,0.f};
  f32x4 acc1 = acc0, acc2 = acc0, acc3 = acc0;

  for (int st = 0; st < steps; ++st) {
    const int k0 = k_base + st * 32;
#pragma unroll
    for (int p = 0; p < 2; ++p) {
      const int r = rowA + p*32;
      const int t = t0 + r;
      const int k = k0 + slotA*4;
      float4 val = make_float4(0.f, 0.f, 0.f, 0.f);
      if (t < TDATA) {
        if (k + 4 <= K) {
          val = *(const float4*)(S + (size_t)t*K + k);
        } else {
          val.x = (k+0 < K) ? S[(size_t)t*K + k+0] : 0.f;
          val.y = (k+1 < K) ? S[(size_t)t*K + k+1] : 0.f;
          val.z = (k+2 < K) ? S[(size_t)t*K + k+2] : 0.f;
          val.w = (k+3 < K) ? S[(size_t)t*K + k+3] : 0.f;
        }
      }
      ushort4 w4;
      w4.x = f2bf(val.x); w4.y = f2bf(val.y);
      w4.z = f2bf(val.z); w4.w = f2bf(val.w);
      *(ushort4*)(&lds.s.A[r*40 + slotA*4]) = w4;
    }
    *(uint4*)(&lds.s.B[cB*40 + slotB*8]) =
        *(const uint4*)(Wg + (size_t)cB*Wstride + k0 + slotB*8);
    __syncthreads();
    // frag: A[m=lane&15][k=quad*8+j], B[n=lane&15][k=quad*8+j]
    const bf16x8 a  = *(const bf16x8*)(&lds.s.A[(wave*16 + m16)*40 + quad*8]);
    const bf16x8 b0 = *(const bf16x8*)(&lds.s.B[(      m16)*40 + quad*8]);
    const bf16x8 b1 = *(const bf16x8*)(&lds.s.B[(16 + m16)*40 + quad*8]);
    const bf16x8 b2 = *(const bf16x8*)(&lds.s.B[(32 + m16)*40 + quad*8]);
    const bf16x8 b3 = *(const bf16x8*)(&lds.s.B[(48 + m16)*40 + quad*8]);
    acc0 = __builtin_amdgcn_mfma_f32_16x16x32_bf16(a, b0, acc0, 0, 0, 0);
    acc1 = __builtin_amdgcn_mfma_f32_16x16x32_bf16(a, b1, acc1, 0, 0, 0);
    acc2 = __builtin_amdgcn_mfma_f32_16x16x32_bf16(a, b2, acc2, 0, 0, 0);
    acc3 = __builtin_amdgcn_mfma_f32_16x16x32_bf16(a, b3, acc3, 0, 0, 0);
    __syncthreads();
  }
  // epilogue: D row=(quad*4+r) -> t-local, col=m16 -> c; transpose via LDS
  // stride 67 (odd*?) -> b32 writes <=2-way conflict, b32 reads conflict-free
  const int rloc = wave*16 + quad*4;
#pragma unroll
  for (int r = 0; r < 4; ++r) {
    lds.C[(      m16)*67 + rloc + r] = acc0[r];
    lds.C[(16 + m16)*67 + rloc + r] = acc1[r];
    lds.C[(32 + m16)*67 + rloc + r] = acc2[r];
    lds.C[(48 + m16)*67 + rloc + r] = acc3[r];
  }
  __syncthreads();
  if (cB < 60) {
    float* o = outp + (size_t)cB * TDATA;
#pragma unroll
    for (int g = 0; g < 16; ++g) {
      const int tl = slotB*16 + g;
      const int t = t0 + tl;
      if (t < TDATA) {
        const float val = lds.C[cB*67 + tl];
        if (isE) atomicAdd(o + t, val);
        else     o[t] = val;
      }
    }
  }
}

// ---------------------------------------------------------------------------
// K3: 201-tap causal FIR per (var,s): syn = conv(IN_e,ke) + conv(IN_i,ki)
//     thread owns 8 consecutive t; register sliding window; swizzled LDS
// ---------------------------------------------------------------------------
__device__ __forceinline__ int swz(int i) { return i + (i >> 5); }

__global__ __launch_bounds__(256) void conv_kernel(
    const float* __restrict__ in_e, const float* __restrict__ in_i,
    const float* __restrict__ kern, float* __restrict__ syn)
{
  __shared__ float Ee[2320];
  __shared__ float Ei[2320];
  const int ch = blockIdx.y;            // var*20 + s
  const int t0 = blockIdx.x * 2048;
  const int s  = ch % SUBS;
  const float* pe = in_e + (size_t)ch * TDATA;
  const float* pi = in_i + (size_t)ch * TDATA;
  for (int i = threadIdx.x; i < 2248; i += 256) {
    const int g = t0 - 200 + i;
    const bool ok = (g >= 0) && (g < TDATA);
    Ee[swz(i)] = ok ? pe[g] : 0.f;
    Ei[swz(i)] = ok ? pi[g] : 0.f;
  }
  __syncthreads();
  const float* ke = kern + (size_t)(s*2    ) * TAPS;
  const float* ki = kern + (size_t)(s*2 + 1) * TAPS;
  const int tb = threadIdx.x * 8;
  float acc[8] = {0.f,0.f,0.f,0.f,0.f,0.f,0.f,0.f};
  float we[8], wi[8];
#pragma unroll
  for (int j = 0; j < 8; ++j) {
    we[j] = Ee[swz(tb + 200 + j)];
    wi[j] = Ei[swz(tb + 200 + j)];
  }
#pragma unroll 8
  for (int m = 0; m < TAPS; ++m) {
    const float k0 = ke[m];
    const float k1 = ki[m];
#pragma unroll
    for (int j = 0; j < 8; ++j)
      acc[j] = fmaf(we[j], k0, fmaf(wi[j], k1, acc[j]));
    if (m < TAPS - 1) {
#pragma unroll
      for (int j = 7; j > 0; --j) { we[j] = we[j-1]; wi[j] = wi[j-1]; }
      we[0] = Ee[swz(tb + 199 - m)];
      wi[0] = Ei[swz(tb + 199 - m)];
    }
  }
  const int t = t0 + tb;
  if (t < TDATA) {
    float* o = syn + (size_t)ch * TDATA + t;
    *(float4*)(o    ) = make_float4(acc[0], acc[1], acc[2], acc[3]);
    *(float4*)(o + 4) = make_float4(acc[4], acc[5], acc[6], acc[7]);
  }
}

// ---------------------------------------------------------------------------
// K4: tanh tree combine -> V outputs
// ---------------------------------------------------------------------------
__global__ __launch_bounds__(256) void tree_kernel(
    const float* __restrict__ syn, const float* __restrict__ W_sub,
    const float* __restrict__ V_o, float* __restrict__ out)
{
  const int t = blockIdx.x * 256 + threadIdx.x;
  const int var = blockIdx.y;
  if (t >= TDATA) return;
  const float* sp = syn + (size_t)var * SUBS * TDATA + t;
  float so[SUBS];
#pragma unroll
  for (int s = SUBS - 1; s >= 0; --s) {
    float val = sp[(size_t)s * TDATA];
    const int c1 = 2*s + 1, c2 = 2*s + 2;
    if (c1 < SUBS) val += so[c1] * W_sub[c1];
    if (c2 < SUBS) val += so[c2] * W_sub[c2];
    so[s] = tanhf(val);
  }
  out[(size_t)var * TDATA + t] = so[0] * W_sub[0] + V_o[0];
}

extern "C" void kernel_launch(void* const* d_in, const int* in_sizes, int n_in,
                              void* d_out, int out_size, void* d_ws, size_t ws_size,
                              hipStream_t stream) {
  const float* S_e     = (const float*)d_in[0];
  const float* S_i     = (const float*)d_in[1];
  const float* u       = (const float*)d_in[2];
  const float* v       = (const float*)d_in[3];
  const float* W_syn   = (const float*)d_in[4];
  const float* Tau_syn = (const float*)d_in[5];
  const float* Delta   = (const float*)d_in[6];
  const float* W_sub   = (const float*)d_in[7];
  const float* V_o     = (const float*)d_in[8];
  const float* C_log   = (const float*)d_in[10];   // d_in[9] = Theta, unused
  float* out = (float*)d_out;
  char* ws = (char*)d_ws;
  unsigned short* wge = (unsigned short*)(ws + WGE_OFF);
  unsigned short* wgi = (unsigned short*)(ws + WGI_OFF);
  float* kern = (float*)(ws + KERN_OFF);
  float* in_e = (float*)(ws + INE_OFF);
  float* in_i = (float*)(ws + INI_OFF);
  float* syn  = (float*)(ws + SYN_OFF);

  prep_kernel<<<dim3(11 + ZERO_BLOCKS), dim3(256), 0, stream>>>(
      u, v, C_log, W_syn, Tau_syn, Delta, out, wge, wgi, kern, in_e);
  gemm_kernel<<<dim3(313, 5), dim3(256), 0, stream>>>(S_e, S_i, wge, wgi, in_e, in_i);
  conv_kernel<<<dim3(10, 60), dim3(256), 0, stream>>>(in_e, in_i, kern, syn);
  tree_kernel<<<dim3(79, 3), dim3(256), 0, stream>>>(syn, W_sub, V_o, out);
}

// Round 3
// 343.619 us; speedup vs baseline: 1.6880x; 1.6880x over previous
//
#include <hip/hip_runtime.h>
#include <math.h>

#define SUBS 20
#define TAPS 201
#define ENO 2000
#define INO 500
#define TDATA 20000

typedef __bf16 bf16x8 __attribute__((ext_vector_type(8)));
typedef float f32x4 __attribute__((ext_vector_type(4)));

#define WGE_STRIDE 2048
#define WGI_STRIDE 512

// workspace byte offsets
#define WGE_OFF  0ull                    // ushort[64*2048] bf16 weights (E)
#define WGI_OFF  262144ull               // ushort[64*512]  bf16 weights (I)
#define KERN_OFF 327680ull               // float[40*201]   synapse kernels
#define INE_OFF  360448ull               // float[60*20000] filtered-input E
#define INI_OFF  (INE_OFF + 4800000ull)  // float[60*20000] filtered-input I
#define SYN_OFF  (INI_OFF + 4800000ull)  // float[60*20000] syn / E-partial scratch

__device__ __forceinline__ unsigned short f2bf(float f) {
  union { float f; unsigned int u; } c; c.f = f;
  unsigned int u = c.u;
  return (unsigned short)((u + 0x7FFFu + ((u >> 16) & 1u)) >> 16);  // RTNE
}

// ---------------------------------------------------------------------------
// K1: per-column prep (theta, hard/soft/softb) + kern filters + weight pads
// ---------------------------------------------------------------------------
__global__ __launch_bounds__(256) void prep_kernel(
    const float* __restrict__ u, const float* __restrict__ v,
    const float* __restrict__ C_log, const float* __restrict__ W_syn,
    const float* __restrict__ Tau_syn, const float* __restrict__ Delta_syn,
    float* __restrict__ out,
    unsigned short* __restrict__ wge, unsigned short* __restrict__ wgi,
    float* __restrict__ kern)
{
  if (blockIdx.x < 10) {
    const int n = blockIdx.x * 256 + threadIdx.x;
    if (n >= 2500) return;
    float x[SUBS], theta[SUBS], rebar[SUBS];
    float mx = -1e30f;
#pragma unroll
    for (int s = 0; s < SUBS; ++s) { x[s] = C_log[s*2500 + n]; mx = fmaxf(mx, x[s]); }
    float sum = 0.f;
#pragma unroll
    for (int s = 0; s < SUBS; ++s) { theta[s] = expf(x[s] - mx); sum += theta[s]; }
    const float inv = 1.f / sum;
    int idx = 0; float best = -1e30f;
#pragma unroll
    for (int s = 0; s < SUBS; ++s) {
      theta[s] *= inv;
      out[60000 + s*2500 + n] = theta[s];
      const float uu = u[s*2500 + n];
      const float r = logf(theta[s]) - logf(-logf(uu));
      rebar[s] = r;
      if (r > best) { best = r; idx = s; }   // first-wins strict >
    }
    const float lvk = logf(v[idx*2500 + n]);
#pragma unroll
    for (int s = 0; s < SUBS; ++s) {
      const float hz = (s == idx) ? 1.f : 0.f;
      const float sz = 1.f / (1.f + expf(-2.f * rebar[s])) + 1e-9f;
      const float vv = v[s*2500 + n];
      const float zb = (s == idx) ? (-logf(-logf(vv)))
                                  : (-logf(-logf(vv) / theta[s] - lvk));
      const float szb = 1.f / (1.f + expf(-2.f * zb)) + 1e-9f;
      out[110000 + s*2500 + n] = hz;
      out[160000 + s*2500 + n] = sz;
      out[210000 + s*2500 + n] = szb;
      if (n < ENO) {
        wge[(s     )*WGE_STRIDE + n] = f2bf(hz);
        wge[(20 + s)*WGE_STRIDE + n] = f2bf(sz);
        wge[(40 + s)*WGE_STRIDE + n] = f2bf(szb);
      } else {
        const int k = n - ENO;
        wgi[(s     )*WGI_STRIDE + k] = f2bf(hz);
        wgi[(20 + s)*WGI_STRIDE + k] = f2bf(sz);
        wgi[(40 + s)*WGI_STRIDE + k] = f2bf(szb);
      }
    }
  } else {
    const int tid = threadIdx.x;
    for (int i = tid; i < 40*TAPS; i += 256) {
      const int ch = i / TAPS, m = i - ch*TAPS;
      const float dl  = expf(Delta_syn[ch]);
      const float tau = expf(Tau_syn[ch]);
      const float t  = fmaxf((float)m - dl, 0.f);
      const float tt = t / tau;
      kern[i] = tt * expf(-tt) * W_syn[ch];
    }
    // zero the padded weight regions (ws is poisoned 0xAA every launch)
    for (int i = tid; i < 4*2048; i += 256) wge[(60 + (i >> 11))*WGE_STRIDE + (i & 2047)] = 0;
    for (int i = tid; i < 60*48;  i += 256) wge[(i / 48)*WGE_STRIDE + 2000 + (i % 48)] = 0;
    for (int i = tid; i < 4*512;  i += 256) wgi[(60 + (i >> 9))*WGI_STRIDE + (i & 511)] = 0;
    for (int i = tid; i < 60*12;  i += 256) wgi[(i / 12)*WGI_STRIDE + 500 + (i % 12)] = 0;
  }
}

// ---------------------------------------------------------------------------
// K2: bf16 MFMA GEMM, split-K without atomics.
//     grid.y: 0 = E k[0,1024) -> in_e ; 1 = E k[1024,2016) -> part (syn scratch)
//             2 = I           -> in_i
//     Epilogue: direct float4 stores from MFMA C-layout (acc[r] = consecutive t)
// ---------------------------------------------------------------------------
__global__ __launch_bounds__(256) void gemm_kernel(
    const float* __restrict__ S_e, const float* __restrict__ S_i,
    const unsigned short* __restrict__ wge, const unsigned short* __restrict__ wgi,
    float* __restrict__ in_e, float* __restrict__ in_i, float* __restrict__ part)
{
  __shared__ unsigned short Alds[64*40];   // [t-row][k] bf16, stride 40 (pad)
  __shared__ unsigned short Blds[64*40];   // [c-row][k] bf16, stride 40
  const int tid  = threadIdx.x;
  const int t0   = blockIdx.x * 64;
  const int chunk = blockIdx.y;          // 0,1 = E halves; 2 = I
  const bool isE = (chunk < 2);
  const int wave = tid >> 6;
  const int lane = tid & 63;
  const int m16  = lane & 15;
  const int quad = lane >> 4;
  const int slotA = tid & 7;   // float4 slot along k
  const int rowA  = tid >> 3;  // 32 rows/pass
  const int cB    = tid >> 2;
  const int slotB = tid & 3;

  const float* S = isE ? S_e : S_i;
  const unsigned short* Wg = isE ? wge : wgi;
  float* outp = (chunk == 0) ? in_e : ((chunk == 1) ? part : in_i);
  const int K       = isE ? ENO : INO;
  const int Wstride = isE ? WGE_STRIDE : WGI_STRIDE;
  const int k_base  = (chunk == 1) ? 1024 : 0;
  const int steps   = (chunk == 0) ? 32 : ((chunk == 1) ? 31 : 16);

  f32x4 acc0 = {0.f,0.f,0.f,0.f};
  f32x4 acc1 = acc0, acc2 = acc0, acc3 = acc0;

  for (int st = 0; st < steps; ++st) {
    const int k0 = k_base + st * 32;
#pragma unroll
    for (int p = 0; p < 2; ++p) {
      const int r = rowA + p*32;
      const int t = t0 + r;
      const int k = k0 + slotA*4;
      float4 val = make_float4(0.f, 0.f, 0.f, 0.f);
      if (t < TDATA) {
        if (k + 4 <= K) {
          val = *(const float4*)(S + (size_t)t*K + k);
        } else {
          val.x = (k+0 < K) ? S[(size_t)t*K + k+0] : 0.f;
          val.y = (k+1 < K) ? S[(size_t)t*K + k+1] : 0.f;
          val.z = (k+2 < K) ? S[(size_t)t*K + k+2] : 0.f;
          val.w = (k+3 < K) ? S[(size_t)t*K + k+3] : 0.f;
        }
      }
      ushort4 w4;
      w4.x = f2bf(val.x); w4.y = f2bf(val.y);
      w4.z = f2bf(val.z); w4.w = f2bf(val.w);
      *(ushort4*)(&Alds[r*40 + slotA*4]) = w4;
    }
    *(uint4*)(&Blds[cB*40 + slotB*8]) =
        *(const uint4*)(Wg + (size_t)cB*Wstride + k0 + slotB*8);
    __syncthreads();
    // frag: A[m=lane&15][k=quad*8+j], B[n=lane&15][k=quad*8+j]
    const bf16x8 a  = *(const bf16x8*)(&Alds[(wave*16 + m16)*40 + quad*8]);
    const bf16x8 b0 = *(const bf16x8*)(&Blds[(      m16)*40 + quad*8]);
    const bf16x8 b1 = *(const bf16x8*)(&Blds[(16 + m16)*40 + quad*8]);
    const bf16x8 b2 = *(const bf16x8*)(&Blds[(32 + m16)*40 + quad*8]);
    const bf16x8 b3 = *(const bf16x8*)(&Blds[(48 + m16)*40 + quad*8]);
    acc0 = __builtin_amdgcn_mfma_f32_16x16x32_bf16(a, b0, acc0, 0, 0, 0);
    acc1 = __builtin_amdgcn_mfma_f32_16x16x32_bf16(a, b1, acc1, 0, 0, 0);
    acc2 = __builtin_amdgcn_mfma_f32_16x16x32_bf16(a, b2, acc2, 0, 0, 0);
    acc3 = __builtin_amdgcn_mfma_f32_16x16x32_bf16(a, b3, acc3, 0, 0, 0);
    __syncthreads();
  }
  // epilogue: C/D layout col=m16 -> c, row=quad*4+r -> t-local. acc[0..3] are
  // 4 consecutive t for one c -> one float4 store per acc, no LDS transpose.
  const int t = t0 + wave*16 + quad*4;
  if (t < TDATA) {
    float* o = outp + t;
    *(float4*)(o + (size_t)(     m16)*TDATA) = *(float4*)&acc0;
    *(float4*)(o + (size_t)(16 + m16)*TDATA) = *(float4*)&acc1;
    *(float4*)(o + (size_t)(32 + m16)*TDATA) = *(float4*)&acc2;
    if (m16 < 12)
      *(float4*)(o + (size_t)(48 + m16)*TDATA) = *(float4*)&acc3;
  }
}

// ---------------------------------------------------------------------------
// K2b: in_e += part  (E split-K reduction, coalesced float4)
// ---------------------------------------------------------------------------
__global__ __launch_bounds__(256) void reduce_kernel(
    float* __restrict__ in_e, const float* __restrict__ part)
{
  const int i = blockIdx.x * 256 + threadIdx.x;
  const int n4 = 60 * TDATA / 4;   // 300000
  if (i < n4) {
    float4 a = ((const float4*)in_e)[i];
    const float4 p = ((const float4*)part)[i];
    a.x += p.x; a.y += p.y; a.z += p.z; a.w += p.w;
    ((float4*)in_e)[i] = a;
  }
}

// ---------------------------------------------------------------------------
// K3: 201-tap causal FIR per (var,s): syn = conv(IN_e,ke) + conv(IN_i,ki)
// ---------------------------------------------------------------------------
__device__ __forceinline__ int swz(int i) { return i + (i >> 5); }

__global__ __launch_bounds__(256) void conv_kernel(
    const float* __restrict__ in_e, const float* __restrict__ in_i,
    const float* __restrict__ kern, float* __restrict__ syn)
{
  __shared__ float Ee[2320];
  __shared__ float Ei[2320];
  const int ch = blockIdx.y;            // var*20 + s
  const int t0 = blockIdx.x * 2048;
  const int s  = ch % SUBS;
  const float* pe = in_e + (size_t)ch * TDATA;
  const float* pi = in_i + (size_t)ch * TDATA;
  for (int i = threadIdx.x; i < 2248; i += 256) {
    const int g = t0 - 200 + i;
    const bool ok = (g >= 0) && (g < TDATA);
    Ee[swz(i)] = ok ? pe[g] : 0.f;
    Ei[swz(i)] = ok ? pi[g] : 0.f;
  }
  __syncthreads();
  const float* ke = kern + (size_t)(s*2    ) * TAPS;
  const float* ki = kern + (size_t)(s*2 + 1) * TAPS;
  const int tb = threadIdx.x * 8;
  float acc[8] = {0.f,0.f,0.f,0.f,0.f,0.f,0.f,0.f};
  float we[8], wi[8];
#pragma unroll
  for (int j = 0; j < 8; ++j) {
    we[j] = Ee[swz(tb + 200 + j)];
    wi[j] = Ei[swz(tb + 200 + j)];
  }
#pragma unroll 8
  for (int m = 0; m < TAPS; ++m) {
    const float k0 = ke[m];
    const float k1 = ki[m];
#pragma unroll
    for (int j = 0; j < 8; ++j)
      acc[j] = fmaf(we[j], k0, fmaf(wi[j], k1, acc[j]));
    if (m < TAPS - 1) {
#pragma unroll
      for (int j = 7; j > 0; --j) { we[j] = we[j-1]; wi[j] = wi[j-1]; }
      we[0] = Ee[swz(tb + 199 - m)];
      wi[0] = Ei[swz(tb + 199 - m)];
    }
  }
  const int t = t0 + tb;
  if (t < TDATA) {
    float* o = syn + (size_t)ch * TDATA + t;
    *(float4*)(o    ) = make_float4(acc[0], acc[1], acc[2], acc[3]);
    *(float4*)(o + 4) = make_float4(acc[4], acc[5], acc[6], acc[7]);
  }
}

// ---------------------------------------------------------------------------
// K4: tanh tree combine -> V outputs
// ---------------------------------------------------------------------------
__global__ __launch_bounds__(256) void tree_kernel(
    const float* __restrict__ syn, const float* __restrict__ W_sub,
    const float* __restrict__ V_o, float* __restrict__ out)
{
  const int t = blockIdx.x * 256 + threadIdx.x;
  const int var = blockIdx.y;
  if (t >= TDATA) return;
  const float* sp = syn + (size_t)var * SUBS * TDATA + t;
  float so[SUBS];
#pragma unroll
  for (int s = SUBS - 1; s >= 0; --s) {
    float val = sp[(size_t)s * TDATA];
    const int c1 = 2*s + 1, c2 = 2*s + 2;
    if (c1 < SUBS) val += so[c1] * W_sub[c1];
    if (c2 < SUBS) val += so[c2] * W_sub[c2];
    so[s] = tanhf(val);
  }
  out[(size_t)var * TDATA + t] = so[0] * W_sub[0] + V_o[0];
}

extern "C" void kernel_launch(void* const* d_in, const int* in_sizes, int n_in,
                              void* d_out, int out_size, void* d_ws, size_t ws_size,
                              hipStream_t stream) {
  const float* S_e     = (const float*)d_in[0];
  const float* S_i     = (const float*)d_in[1];
  const float* u       = (const float*)d_in[2];
  const float* v       = (const float*)d_in[3];
  const float* W_syn   = (const float*)d_in[4];
  const float* Tau_syn = (const float*)d_in[5];
  const float* Delta   = (const float*)d_in[6];
  const float* W_sub   = (const float*)d_in[7];
  const float* V_o     = (const float*)d_in[8];
  const float* C_log   = (const float*)d_in[10];   // d_in[9] = Theta, unused
  float* out = (float*)d_out;
  char* ws = (char*)d_ws;
  unsigned short* wge = (unsigned short*)(ws + WGE_OFF);
  unsigned short* wgi = (unsigned short*)(ws + WGI_OFF);
  float* kern = (float*)(ws + KERN_OFF);
  float* in_e = (float*)(ws + INE_OFF);
  float* in_i = (float*)(ws + INI_OFF);
  float* syn  = (float*)(ws + SYN_OFF);   // doubles as E-partial before conv

  prep_kernel<<<dim3(11), dim3(256), 0, stream>>>(u, v, C_log, W_syn, Tau_syn,
                                                  Delta, out, wge, wgi, kern);
  gemm_kernel<<<dim3(313, 3), dim3(256), 0, stream>>>(S_e, S_i, wge, wgi,
                                                      in_e, in_i, syn);
  reduce_kernel<<<dim3(1172), dim3(256), 0, stream>>>(in_e, syn);
  conv_kernel<<<dim3(10, 60), dim3(256), 0, stream>>>(in_e, in_i, kern, syn);
  tree_kernel<<<dim3(79, 3), dim3(256), 0, stream>>>(syn, W_sub, V_o, out);
}